// Round 12
// baseline (1481.155 us; speedup 1.0000x reference)
//
#include <hip/hip_runtime.h>
#include <math.h>

#define NN 100000
#define GSZ 128                    // nodes per gather bucket
#define NB 782                     // ceil(NN/GSZ) buckets per half
#define NB2 1564                   // both halves
#define RBSLOTS 50048              // finalize scratch slots per half (unchanged)
constexpr float MAXNORM_C = 0.996f;   // (1 - 4e-3)/sqrt(c), c=1
constexpr float MINNORM_C = 1e-15f;

// ---------- prep: transpose the 4 weight matrices into ws ----------
__global__ void prep_transpose(const float* __restrict__ Wp, const float* __restrict__ Wpc,
                               const float* __restrict__ Wn, const float* __restrict__ Wnc,
                               float* __restrict__ wt) {
    int idx = blockIdx.x * 256 + threadIdx.x;   // 0..16383
    int m = idx >> 12;
    int k = (idx >> 6) & 63;
    int j = idx & 63;
    const float* W = (m == 0) ? Wp : (m == 1) ? Wpc : (m == 2) ? Wn : Wnc;
    wt[idx] = W[j * 64 + k];
}

__device__ inline float wave_sum64(float v) {
    #pragma unroll
    for (int m = 32; m >= 1; m >>= 1) v += __shfl_xor(v, m, 64);
    return v;
}

// ---------- prep: hyp_bias = proj(expmap0(b, c), c), plus its |.|^2 ----------
__global__ void prep_bias(const float* __restrict__ bp, const float* __restrict__ bn,
                          float* __restrict__ hb) {
    int l = threadIdx.x;   // one wave
    #pragma unroll
    for (int h = 0; h < 2; ++h) {
        float u = (h ? bn : bp)[l];
        float norm = fmaxf(sqrtf(wave_sum64(u * u)), MINNORM_C);
        float s = tanhf(norm) / norm;          // sqrt_c = 1
        float v = s * u;
        float vn = fmaxf(sqrtf(wave_sum64(v * v)), MINNORM_C);
        if (vn > MAXNORM_C) v *= MAXNORM_C / vn;
        float y2 = wave_sum64(v * v);
        hb[h * 65 + l] = v;
        if (l == 0) hb[h * 65 + 64] = y2;
    }
}

// ---------- bucket count: per-block LDS histogram -> global atomics ----------
__global__ __launch_bounds__(256) void bucket_count(
    const int* __restrict__ pei, int E1,
    const int* __restrict__ nei, int E2,
    int* __restrict__ gcnt) {
    __shared__ int h[NB2];
    int tid = threadIdx.x;
    for (int i = tid; i < NB2; i += 256) h[i] = 0;
    __syncthreads();
    int tot = E1 + E2;
    int base = blockIdx.x * 8192;
    #pragma unroll 4
    for (int k = 0; k < 32; ++k) {
        int idx = base + k * 256 + tid;
        if (idx < tot) {
            int half = idx >= E1;
            int e = idx - (half ? E1 : 0);
            const int* ei = half ? nei : pei;
            int E = half ? E2 : E1;
            int dst = ei[E + e];
            atomicAdd(&h[half * NB + (dst >> 7)], 1);
        }
    }
    __syncthreads();
    for (int i = tid; i < NB2; i += 256) {
        int c = h[i];
        if (c) atomicAdd(&gcnt[i], c);
    }
}

// ---------- exclusive scan of NB2 bucket counts (single block) ----------
__global__ void bucket_scan(const int* __restrict__ gcnt, int* __restrict__ goffs,
                            int* __restrict__ gcursor) {
    __shared__ int tmp[256];
    int tid = threadIdx.x;
    int base = tid * 8;
    int items[8];
    int s = 0;
    #pragma unroll
    for (int i = 0; i < 8; ++i) {
        items[i] = (base + i < NB2) ? gcnt[base + i] : 0;
        s += items[i];
    }
    tmp[tid] = s;
    __syncthreads();
    for (int off = 1; off < 256; off <<= 1) {
        int v = (tid >= off) ? tmp[tid - off] : 0;
        __syncthreads();
        tmp[tid] += v;
        __syncthreads();
    }
    int run = tmp[tid] - s;
    #pragma unroll
    for (int i = 0; i < 8; ++i) {
        if (base + i < NB2) { goffs[base + i] = run; gcursor[base + i] = run; }
        run += items[i];
    }
}

// ---------- bucket scatter: two-pass block aggregation, packed writes ----------
// packed edge = (src << 7) | (dst & 127)   (src < 2^17, fits 24 bits)
__global__ __launch_bounds__(256) void bucket_scatter(
    const int* __restrict__ pei, int E1,
    const int* __restrict__ nei, int E2,
    int* __restrict__ gcursor, int* __restrict__ packed) {
    __shared__ int h[NB2];
    __shared__ int hb[NB2];
    int tid = threadIdx.x;
    for (int i = tid; i < NB2; i += 256) h[i] = 0;
    __syncthreads();
    int tot = E1 + E2;
    int base = blockIdx.x * 8192;
    // pass A: histogram
    #pragma unroll 4
    for (int k = 0; k < 32; ++k) {
        int idx = base + k * 256 + tid;
        if (idx < tot) {
            int half = idx >= E1;
            int e = idx - (half ? E1 : 0);
            const int* ei = half ? nei : pei;
            int E = half ? E2 : E1;
            int dst = ei[E + e];
            atomicAdd(&h[half * NB + (dst >> 7)], 1);
        }
    }
    __syncthreads();
    // reserve chunks
    for (int i = tid; i < NB2; i += 256) {
        int c = h[i];
        hb[i] = c ? atomicAdd(&gcursor[i], c) : 0;
    }
    __syncthreads();
    for (int i = tid; i < NB2; i += 256) h[i] = 0;
    __syncthreads();
    // pass B: claim local rank, write packed
    #pragma unroll 4
    for (int k = 0; k < 32; ++k) {
        int idx = base + k * 256 + tid;
        if (idx < tot) {
            int half = idx >= E1;
            int e = idx - (half ? E1 : 0);
            const int* ei = half ? nei : pei;
            int E = half ? E2 : E1;
            int src = ei[e];
            int dst = ei[E + e];
            int b = half * NB + (dst >> 7);
            int r = atomicAdd(&h[b], 1);
            packed[hb[b] + r] = (src << 7) | (dst & 127);
        }
    }
}

// ---------- fused bucket-gather: one block per bucket, LDS accumulators ----------
// Replaces node_sort + gather: consumes bucket-grouped packed edges directly,
// accumulating into LDS acc[128][64] via float atomics (64 lanes -> consecutive
// floats -> 2-way bank aliasing = free, m136). Also counts deg per node.
// 512 thr (8 waves), LDS 33 KB -> 4 blocks/CU -> 32 waves/CU (full occupancy;
// old gather ran at 78%). Deletes node_sort (~40-60 us) + esrc/ndeg/noffs
// traffic (~64 MB). The random 256-B x-row fetch pattern is unchanged
// (R11-measured floor: 357 MB fill at ~3 TB/s).
__global__ __launch_bounds__(512) void bucket_gather(
    const int* __restrict__ goffs, const int* __restrict__ gcnt,
    const int* __restrict__ packed, const float* __restrict__ x,
    float* __restrict__ out) {
    __shared__ __align__(16) float acc[GSZ * 64];
    __shared__ int deg[GSZ];
    int tid = threadIdx.x;
    int bucket = blockIdx.x;
    int half = bucket >= NB;
    int b = bucket - (half ? NB : 0);
    int start = goffs[bucket];
    int cnt = gcnt[bucket];
    #pragma unroll
    for (int i = 0; i < 16; ++i) acc[i * 512 + tid] = 0.f;
    if (tid < GSZ) deg[tid] = 0;
    __syncthreads();

    int lane = tid & 63;
    int end = start + cnt;
    for (int base0 = start + (tid >> 6) * 64; base0 < end; base0 += 512) {
        int n = min(64, end - base0);
        int p_l = (base0 + lane < end) ? packed[base0 + lane] : 0;
        if (lane < n) atomicAdd(&deg[p_l & 127], 1);
        int i = 0;
        for (; i + 4 <= n; i += 4) {
            int p0 = __shfl(p_l, i, 64), p1 = __shfl(p_l, i + 1, 64);
            int p2 = __shfl(p_l, i + 2, 64), p3 = __shfl(p_l, i + 3, 64);
            float v0 = x[(p0 >> 7) * 64 + lane];
            float v1 = x[(p1 >> 7) * 64 + lane];
            float v2 = x[(p2 >> 7) * 64 + lane];
            float v3 = x[(p3 >> 7) * 64 + lane];
            atomicAdd(&acc[(p0 & 127) * 64 + lane], v0);
            atomicAdd(&acc[(p1 & 127) * 64 + lane], v1);
            atomicAdd(&acc[(p2 & 127) * 64 + lane], v2);
            atomicAdd(&acc[(p3 & 127) * 64 + lane], v3);
        }
        for (; i < n; ++i) {
            int p = __shfl(p_l, i, 64);
            atomicAdd(&acc[(p & 127) * 64 + lane], x[(p >> 7) * 64 + lane]);
        }
    }
    __syncthreads();

    // write MEAN to out[node*128 + half*64 + f]
    int nodebase = b * GSZ;
    #pragma unroll
    for (int k = 0; k < 4; ++k) {
        int idx4 = k * 512 + tid;            // 2048 float4 slots
        int nl = idx4 >> 4;                  // local node
        int f0 = (idx4 & 15) * 4;
        int gnode = nodebase + nl;
        if (gnode < NN) {
            float d = fmaxf((float)deg[nl], 1.f);
            float4 v = *(const float4*)&acc[nl * 64 + f0];
            *(float4*)&out[(size_t)gnode * 128 + half * 64 + f0] =
                make_float4(v.x / d, v.y / d, v.z / d, v.w / d);
        }
    }
}

// ---------- matvec, weights via LDS broadcast (LDS pipe) ----------
__device__ __attribute__((always_inline)) inline void mm1_lds(
        const float* p, const float4* wl, float (&m)[64], float& vn2out) {
    #pragma unroll
    for (int j = 0; j < 64; ++j) m[j] = 0.f;
    float vn2 = 0.f;
    #pragma unroll 1
    for (int k0 = 0; k0 < 64; k0 += 4) {    // rolled: I$-friendly
        float4 a = *(const float4*)(p + k0);
        vn2 = fmaf(a.x, a.x, fmaf(a.y, a.y, fmaf(a.z, a.z, fmaf(a.w, a.w, vn2))));
        const float4* wk = wl + k0 * 16;
        #pragma unroll
        for (int j4 = 0; j4 < 16; ++j4) {
            float4 w0 = wk[j4];          // ds_read_b128, uniform addr -> broadcast
            float4 w1 = wk[16 + j4];
            float4 w2 = wk[32 + j4];
            float4 w3 = wk[48 + j4];
            int j = j4 * 4;
            m[j+0] = fmaf(a.x,w0.x, fmaf(a.y,w1.x, fmaf(a.z,w2.x, fmaf(a.w,w3.x, m[j+0]))));
            m[j+1] = fmaf(a.x,w0.y, fmaf(a.y,w1.y, fmaf(a.z,w2.y, fmaf(a.w,w3.y, m[j+1]))));
            m[j+2] = fmaf(a.x,w0.z, fmaf(a.y,w1.z, fmaf(a.z,w2.z, fmaf(a.w,w3.z, m[j+2]))));
            m[j+3] = fmaf(a.x,w0.w, fmaf(a.y,w1.w, fmaf(a.z,w2.w, fmaf(a.w,w3.w, m[j+3]))));
        }
    }
    vn2out = vn2;
}

// ---------- matvec, weights via scalar loads (SMEM pipe) ----------
__device__ __attribute__((always_inline)) inline void mm1_s(
        const float* p, const float* __restrict__ wtm, float (&m)[64], float& vn2out) {
    #pragma unroll
    for (int j = 0; j < 64; ++j) m[j] = 0.f;
    float vn2 = 0.f;
    for (int k0 = 0; k0 < 64; k0 += 4) {
        float4 a = *(const float4*)(p + k0);
        vn2 = fmaf(a.x, a.x, fmaf(a.y, a.y, fmaf(a.z, a.z, fmaf(a.w, a.w, vn2))));
        const float* w0 = wtm + k0 * 64;        // uniform address -> s_load
        #pragma unroll
        for (int j = 0; j < 64; ++j) {
            float mm = m[j];
            mm = fmaf(a.x, w0[j],        mm);
            mm = fmaf(a.y, w0[64 + j],   mm);
            mm = fmaf(a.z, w0[128 + j],  mm);
            mm = fmaf(a.w, w0[192 + j],  mm);
            m[j] = mm;
        }
    }
    vn2out = vn2;
}

// tanh(mx_norm/x_norm * artanh(x_norm)) * mx / mx_norm, then proj — in place.
__device__ __attribute__((always_inline)) inline void mob_scale_proj(
        float (&m)[64], float vn2) {
    float mn2 = 0.f;
    #pragma unroll
    for (int j = 0; j < 64; ++j) mn2 = fmaf(m[j], m[j], mn2);
    float xnorm = fmaxf(sqrtf(vn2), MINNORM_C);
    float mnorm = fmaxf(sqrtf(mn2), MINNORM_C);
    float z = fminf(xnorm, 1.0f - 1e-7f);                   // artanh clip
    float art = 0.5f * logf((1.0f + z) / (1.0f - z));
    float t = tanhf(mnorm / xnorm * art);
    float scale = (mn2 == 0.f) ? 0.f : (t / mnorm);         // zero_mx branch
    #pragma unroll
    for (int j = 0; j < 64; ++j) m[j] *= scale;
    float rn2 = 0.f;
    #pragma unroll
    for (int j = 0; j < 64; ++j) rn2 = fmaf(m[j], m[j], rn2);
    float rnorm = fmaxf(sqrtf(rn2), MINNORM_C);
    float f = (rnorm > MAXNORM_C) ? (MAXNORM_C / rnorm) : 1.0f;   // proj
    #pragma unroll
    for (int j = 0; j < 64; ++j) m[j] *= f;
}

// mobius_add with hyp_bias (in LDS) + proj factor; m updated in place,
// returns final proj scale f (applied at write time).
__device__ __attribute__((always_inline)) inline float bias_addf(
        float (&m)[64], const float* hbv) {
    float x2 = 0.f, xy = 0.f;
    #pragma unroll
    for (int j = 0; j < 64; ++j) {
        float h = hbv[j];
        x2 = fmaf(m[j], m[j], x2);
        xy = fmaf(m[j], h, xy);
    }
    float y2 = hbv[64];
    float A = 1.f + 2.f * xy + y2;
    float Bc = 1.f - x2;
    float den = 1.f + 2.f * xy + x2 * y2;
    float dinv = 1.f / fmaxf(den, MINNORM_C);
    float rn2 = 0.f;
    #pragma unroll
    for (int j = 0; j < 64; ++j) {
        float r = (A * m[j] + Bc * hbv[j]) * dinv;
        m[j] = r;
        rn2 = fmaf(r, r, rn2);
    }
    float rnorm = fmaxf(sqrtf(rn2), MINNORM_C);
    return (rnorm > MAXNORM_C) ? (MAXNORM_C / rnorm) : 1.0f;
}

// ---------- finalize: hybrid pipes + explicit wave stagger (R11, kept) ----------
__global__ __launch_bounds__(256, 2) void finalize_kernel(
    const float* __restrict__ x,
    const float* __restrict__ wt,    // 4 transposed 64x64 matrices
    const float* __restrict__ hb,    // 2 x 65
    float* __restrict__ rb,          // scratch: 2 * RBSLOTS * 64 floats
    float* __restrict__ out) {
    __shared__ float4 wlds[1024];               // W (phase A) only, 16 KB
    __shared__ __align__(16) float hbs[68];
    int tid = threadIdx.x;
    int half = blockIdx.x & 1;

    const float4* wsrc = (const float4*)(wt + half * 8192);
    #pragma unroll
    for (int i = 0; i < 4; ++i) wlds[i * 256 + tid] = wsrc[i * 256 + tid];
    if (tid < 65) hbs[tid] = hb[half * 65 + tid];
    __syncthreads();

    int node = (blockIdx.x >> 1) * 256 + tid;
    bool valid = node < NN;
    int nc = valid ? node : NN - 1;
    float* op = out + (size_t)nc * 128 + half * 64;
    const float* wtb = wt + half * 8192 + 4096;  // W_cc (SMEM-streamed)

    if (tid < 128) {
        // ===== waves 0-1: A (LDS) -> B (SMEM) =====
        {   // phase A: proj(mobius_matvec(W, agg)) -> store resA to out
            float m[64]; float vn2;
            mm1_lds(op, wlds, m, vn2);
            mob_scale_proj(m, vn2);
            if (valid) {
                #pragma unroll
                for (int k0 = 0; k0 < 64; k0 += 4)
                    *(float4*)(op + k0) = make_float4(m[k0], m[k0+1], m[k0+2], m[k0+3]);
            }
        }
        {   // phase B: cc path, add into out (own write, L2-hot)
            float m[64]; float vn2;
            mm1_s(x + (size_t)nc * 64, wtb, m, vn2);
            mob_scale_proj(m, vn2);
            float f = bias_addf(m, hbs);
            if (valid) {
                #pragma unroll
                for (int k0 = 0; k0 < 64; k0 += 4) {
                    float4 a = *(const float4*)(op + k0);
                    a.x += m[k0 + 0] * f;
                    a.y += m[k0 + 1] * f;
                    a.z += m[k0 + 2] * f;
                    a.w += m[k0 + 3] * f;
                    *(float4*)(op + k0) = a;
                }
            }
        }
    } else {
        // ===== waves 2-3: B (SMEM) -> A (LDS) =====
        float* rp = rb + ((size_t)half * RBSLOTS + (size_t)(blockIdx.x >> 1) * 128
                          + (tid - 128)) * 64;
        {   // phase B first: resB*f -> scratch
            float m[64]; float vn2;
            mm1_s(x + (size_t)nc * 64, wtb, m, vn2);
            mob_scale_proj(m, vn2);
            float f = bias_addf(m, hbs);
            if (valid) {
                #pragma unroll
                for (int k0 = 0; k0 < 64; k0 += 4)
                    *(float4*)(rp + k0) = make_float4(m[k0]*f, m[k0+1]*f,
                                                      m[k0+2]*f, m[k0+3]*f);
            }
        }
        {   // phase A: resA + scratch -> out (same-thread store->load, no fence)
            float m[64]; float vn2;
            mm1_lds(op, wlds, m, vn2);
            mob_scale_proj(m, vn2);
            if (valid) {
                #pragma unroll
                for (int k0 = 0; k0 < 64; k0 += 4) {
                    float4 b = *(const float4*)(rp + k0);
                    *(float4*)(op + k0) = make_float4(m[k0+0] + b.x, m[k0+1] + b.y,
                                                      m[k0+2] + b.z, m[k0+3] + b.w);
                }
            }
        }
    }
}

extern "C" void kernel_launch(void* const* d_in, const int* in_sizes, int n_in,
                              void* d_out, int out_size, void* d_ws, size_t ws_size,
                              hipStream_t stream) {
    const float* x   = (const float*)d_in[0];
    const float* Wp  = (const float*)d_in[1];
    const float* Wpc = (const float*)d_in[2];
    const float* bp  = (const float*)d_in[3];
    const float* Wn  = (const float*)d_in[4];
    const float* Wnc = (const float*)d_in[5];
    const float* bn  = (const float*)d_in[6];
    const int* pei = (const int*)d_in[7];
    const int* nei = (const int*)d_in[8];
    float* out = (float*)d_out;

    int E1 = in_sizes[7] / 2;
    int E2 = in_sizes[8] / 2;
    int tot = E1 + E2;

    // ws layout (4-byte units):
    //   gcnt[NB2] | goffs[NB2] | gcursor[NB2] | pad | hb[192] | wt[16384]
    //   | packed[tot] | rsvd[tot] | ...
    // finalize reuses packed+rsvd (dead after bucket_gather) as its 25.6 MB
    // resB scratch (2*RBSLOTS*64 floats).
    int*   gcnt    = (int*)d_ws;
    int*   goffs   = gcnt + NB2;
    int*   gcursor = goffs + NB2;
    float* hbp     = (float*)(gcursor + NB2 + 2);   // align
    float* wt      = hbp + 192;
    int*   packed  = (int*)(wt + 16384);
    float* rb      = (float*)packed;             // reuse (dead at finalize time)

    hipMemsetAsync(gcnt, 0, NB2 * sizeof(int), stream);

    prep_transpose<<<64, 256, 0, stream>>>(Wp, Wpc, Wn, Wnc, wt);
    prep_bias<<<1, 64, 0, stream>>>(bp, bn, hbp);

    int nblk = (tot + 8191) / 8192;    // 391
    bucket_count<<<nblk, 256, 0, stream>>>(pei, E1, nei, E2, gcnt);
    bucket_scan<<<1, 256, 0, stream>>>(gcnt, goffs, gcursor);
    bucket_scatter<<<nblk, 256, 0, stream>>>(pei, E1, nei, E2, gcursor, packed);

    bucket_gather<<<NB2, 512, 0, stream>>>(goffs, gcnt, packed, x, out);

    int fblocks = 2 * ((NN + 255) / 256);        // 782
    finalize_kernel<<<fblocks, 256, 0, stream>>>(x, wt, hbp, rb, out);
}

// Round 13
// 419.694 us; speedup vs baseline: 3.5291x; 3.5291x over previous
//
#include <hip/hip_runtime.h>
#include <math.h>

#define NN 100000
#define BSZ 256                    // nodes per bucket
#define NB 391                     // ceil(NN/BSZ)
#define NB2 782                    // both halves
constexpr float MAXNORM_C = 0.996f;   // (1 - 4e-3)/sqrt(c), c=1
constexpr float MINNORM_C = 1e-15f;

// ---------- prep: transpose the 4 weight matrices into ws ----------
__global__ void prep_transpose(const float* __restrict__ Wp, const float* __restrict__ Wpc,
                               const float* __restrict__ Wn, const float* __restrict__ Wnc,
                               float* __restrict__ wt) {
    int idx = blockIdx.x * 256 + threadIdx.x;   // 0..16383
    int m = idx >> 12;
    int k = (idx >> 6) & 63;
    int j = idx & 63;
    const float* W = (m == 0) ? Wp : (m == 1) ? Wpc : (m == 2) ? Wn : Wnc;
    wt[idx] = W[j * 64 + k];
}

__device__ inline float wave_sum64(float v) {
    #pragma unroll
    for (int m = 32; m >= 1; m >>= 1) v += __shfl_xor(v, m, 64);
    return v;
}

// ---------- prep: hyp_bias = proj(expmap0(b, c), c), plus its |.|^2 ----------
__global__ void prep_bias(const float* __restrict__ bp, const float* __restrict__ bn,
                          float* __restrict__ hb) {
    int l = threadIdx.x;   // one wave
    #pragma unroll
    for (int h = 0; h < 2; ++h) {
        float u = (h ? bn : bp)[l];
        float norm = fmaxf(sqrtf(wave_sum64(u * u)), MINNORM_C);
        float s = tanhf(norm) / norm;          // sqrt_c = 1
        float v = s * u;
        float vn = fmaxf(sqrtf(wave_sum64(v * v)), MINNORM_C);
        if (vn > MAXNORM_C) v *= MAXNORM_C / vn;
        float y2 = wave_sum64(v * v);
        hb[h * 65 + l] = v;
        if (l == 0) hb[h * 65 + 64] = y2;
    }
}

// ---------- bucket count: per-block LDS histogram -> global atomics ----------
__global__ __launch_bounds__(256) void bucket_count(
    const int* __restrict__ pei, int E1,
    const int* __restrict__ nei, int E2,
    int* __restrict__ gcnt) {
    __shared__ int h[NB2];
    int tid = threadIdx.x;
    for (int i = tid; i < NB2; i += 256) h[i] = 0;
    __syncthreads();
    int tot = E1 + E2;
    int base = blockIdx.x * 8192;
    #pragma unroll 4
    for (int k = 0; k < 32; ++k) {
        int idx = base + k * 256 + tid;
        if (idx < tot) {
            int half = idx >= E1;
            int e = idx - (half ? E1 : 0);
            const int* ei = half ? nei : pei;
            int E = half ? E2 : E1;
            int dst = ei[E + e];
            atomicAdd(&h[half * NB + (dst >> 8)], 1);
        }
    }
    __syncthreads();
    for (int i = tid; i < NB2; i += 256) {
        int c = h[i];
        if (c) atomicAdd(&gcnt[i], c);
    }
}

// ---------- exclusive scan of NB2 bucket counts (single block) ----------
__global__ void bucket_scan(const int* __restrict__ gcnt, int* __restrict__ goffs,
                            int* __restrict__ gcursor) {
    __shared__ int tmp[256];
    int tid = threadIdx.x;
    int base = tid * 4;
    int items[4];
    int s = 0;
    #pragma unroll
    for (int i = 0; i < 4; ++i) {
        items[i] = (base + i < NB2) ? gcnt[base + i] : 0;
        s += items[i];
    }
    tmp[tid] = s;
    __syncthreads();
    for (int off = 1; off < 256; off <<= 1) {
        int v = (tid >= off) ? tmp[tid - off] : 0;
        __syncthreads();
        tmp[tid] += v;
        __syncthreads();
    }
    int run = tmp[tid] - s;
    #pragma unroll
    for (int i = 0; i < 4; ++i) {
        if (base + i < NB2) { goffs[base + i] = run; gcursor[base + i] = run; }
        run += items[i];
    }
}

// ---------- bucket scatter: two-pass block aggregation, packed writes ----------
// packed edge = (src << 8) | (dst & 255)   (src < 2^17, fits 25 bits)
__global__ __launch_bounds__(256) void bucket_scatter(
    const int* __restrict__ pei, int E1,
    const int* __restrict__ nei, int E2,
    int* __restrict__ gcursor, int* __restrict__ packed) {
    __shared__ int h[NB2];
    __shared__ int hb[NB2];
    int tid = threadIdx.x;
    for (int i = tid; i < NB2; i += 256) h[i] = 0;
    __syncthreads();
    int tot = E1 + E2;
    int base = blockIdx.x * 8192;
    // pass A: histogram
    #pragma unroll 4
    for (int k = 0; k < 32; ++k) {
        int idx = base + k * 256 + tid;
        if (idx < tot) {
            int half = idx >= E1;
            int e = idx - (half ? E1 : 0);
            const int* ei = half ? nei : pei;
            int E = half ? E2 : E1;
            int dst = ei[E + e];
            atomicAdd(&h[half * NB + (dst >> 8)], 1);
        }
    }
    __syncthreads();
    // reserve chunks
    for (int i = tid; i < NB2; i += 256) {
        int c = h[i];
        hb[i] = c ? atomicAdd(&gcursor[i], c) : 0;
    }
    __syncthreads();
    for (int i = tid; i < NB2; i += 256) h[i] = 0;
    __syncthreads();
    // pass B: claim local rank, write packed
    #pragma unroll 4
    for (int k = 0; k < 32; ++k) {
        int idx = base + k * 256 + tid;
        if (idx < tot) {
            int half = idx >= E1;
            int e = idx - (half ? E1 : 0);
            const int* ei = half ? nei : pei;
            int E = half ? E2 : E1;
            int src = ei[e];
            int dst = ei[E + e];
            int b = half * NB + (dst >> 8);
            int r = atomicAdd(&h[b], 1);
            packed[hb[b] + r] = (src << 8) | (dst & 255);
        }
    }
}

// ---------- node sort: one block per bucket; sort edges to node order ----------
__global__ __launch_bounds__(256) void node_sort(
    const int* __restrict__ goffs, const int* __restrict__ gcnt,
    const int* __restrict__ packed,
    int* __restrict__ esrc, int* __restrict__ ndeg, int* __restrict__ noffs) {
    __shared__ int h[256];
    __shared__ int sc[256];
    int tid = threadIdx.x;
    int bucket = blockIdx.x;
    int start = goffs[bucket];
    int cnt = gcnt[bucket];
    h[tid] = 0;
    __syncthreads();
    for (int i = start + tid; i < start + cnt; i += 256)
        atomicAdd(&h[packed[i] & 255], 1);
    __syncthreads();
    int deg = h[tid];
    // exclusive scan of degrees
    sc[tid] = deg;
    __syncthreads();
    for (int off = 1; off < 256; off <<= 1) {
        int v = (tid >= off) ? sc[tid - off] : 0;
        __syncthreads();
        sc[tid] += v;
        __syncthreads();
    }
    int excl = sc[tid] - deg;
    int half = bucket >= NB;
    int node = (bucket - (half ? NB : 0)) * BSZ + tid;
    if (node < NN) {
        ndeg[half * NN + node] = deg;
        noffs[half * NN + node] = start + excl;
    }
    // reuse h as local cursor
    h[tid] = excl;
    __syncthreads();
    for (int i = start + tid; i < start + cnt; i += 256) {
        int p = packed[i];
        int r = atomicAdd(&h[p & 255], 1);
        esrc[start + r] = p >> 8;
    }
}

// ---------- gather: wave per node-half (high TLP), writes MEAN ----------
// Register accumulation; R12's LDS-atomic variant was 10x worse (1225 us,
// VALU 3%): atomics broke the load-batch ILP. Keep this structure.
__global__ __launch_bounds__(256) void gather_kernel(
    const int* __restrict__ noffs, const int* __restrict__ ndeg,
    const int* __restrict__ esrc, const float* __restrict__ x,
    float* __restrict__ out) {
    int wid = (blockIdx.x * 256 + threadIdx.x) >> 6;   // node-half id, 0..2NN
    int lane = threadIdx.x & 63;
    if (wid >= 2 * NN) return;
    int half = wid >= NN;
    int node = wid - (half ? NN : 0);
    int start = noffs[wid];
    int deg = ndeg[wid];
    float acc = 0.f;
    for (int b = 0; b < deg; b += 64) {
        int n = min(64, deg - b);
        int s_l = (b + lane < deg) ? esrc[start + b + lane] : 0;
        int i = 0;
        for (; i + 4 <= n; i += 4) {
            int a0 = __shfl(s_l, i, 64), a1 = __shfl(s_l, i + 1, 64);
            int a2 = __shfl(s_l, i + 2, 64), a3 = __shfl(s_l, i + 3, 64);
            float v0 = x[a0 * 64 + lane], v1 = x[a1 * 64 + lane];
            float v2 = x[a2 * 64 + lane], v3 = x[a3 * 64 + lane];
            acc += (v0 + v1) + (v2 + v3);
        }
        for (; i < n; ++i) acc += x[__shfl(s_l, i, 64) * 64 + lane];
    }
    float m = acc / fmaxf((float)deg, 1.f);
    out[(size_t)node * 128 + half * 64 + lane] = m;
}

// ---------- matvec, INTRA-WAVE hybrid weight delivery ----------
// R10/R11 lesson: pipe-splitting at phase granularity serializes (lockstep
// waves: 125 us = 62+59). This interleaves at k0-chunk granularity INSIDE
// each matvec: even 4-row chunks read weights from LDS (ds_read_b128
// broadcast), odd chunks stream via s_load (lane-uniform). Every ~600-cycle
// window contains both LDS and SMEM work -> the two pipes overlap
// structurally, independent of wave drift. Each pipe carries half the
// stream. Known risk: ds_read and s_load share lgkmcnt (out-of-order) ->
// compiler may insert full drains per chunk; 16/matvec should still pipeline.
__device__ __attribute__((always_inline)) inline void mm1_hyb(
        const float* p, const float4* wl, const float* __restrict__ ws,
        float (&m)[64], float& vn2out) {
    #pragma unroll
    for (int j = 0; j < 64; ++j) m[j] = 0.f;
    float vn2 = 0.f;
    #pragma unroll 1
    for (int c = 0; c < 8; ++c) {           // chunk-pair: rows 8c..8c+3 (LDS), 8c+4..8c+7 (SMEM)
        float4 a = *(const float4*)(p + c * 8);
        float4 b = *(const float4*)(p + c * 8 + 4);
        vn2 = fmaf(a.x, a.x, fmaf(a.y, a.y, fmaf(a.z, a.z, fmaf(a.w, a.w, vn2))));
        vn2 = fmaf(b.x, b.x, fmaf(b.y, b.y, fmaf(b.z, b.z, fmaf(b.w, b.w, vn2))));
        const float4* wk = wl + c * 64;             // LDS: 4 rows x 16 float4
        const float* w0 = ws + c * 512 + 256;       // SMEM: rows 8c+4..8c+7
        #pragma unroll
        for (int j4 = 0; j4 < 16; ++j4) {
            float4 we0 = wk[j4];
            float4 we1 = wk[16 + j4];
            float4 we2 = wk[32 + j4];
            float4 we3 = wk[48 + j4];
            int j = j4 * 4;
            float m0 = m[j+0], m1 = m[j+1], m2 = m[j+2], m3 = m[j+3];
            m0 = fmaf(a.x,we0.x, fmaf(a.y,we1.x, fmaf(a.z,we2.x, fmaf(a.w,we3.x, m0))));
            m1 = fmaf(a.x,we0.y, fmaf(a.y,we1.y, fmaf(a.z,we2.y, fmaf(a.w,we3.y, m1))));
            m2 = fmaf(a.x,we0.z, fmaf(a.y,we1.z, fmaf(a.z,we2.z, fmaf(a.w,we3.z, m2))));
            m3 = fmaf(a.x,we0.w, fmaf(a.y,we1.w, fmaf(a.z,we2.w, fmaf(a.w,we3.w, m3))));
            m0 = fmaf(b.x,w0[j+0], fmaf(b.y,w0[64+j+0], fmaf(b.z,w0[128+j+0], fmaf(b.w,w0[192+j+0], m0))));
            m1 = fmaf(b.x,w0[j+1], fmaf(b.y,w0[64+j+1], fmaf(b.z,w0[128+j+1], fmaf(b.w,w0[192+j+1], m1))));
            m2 = fmaf(b.x,w0[j+2], fmaf(b.y,w0[64+j+2], fmaf(b.z,w0[128+j+2], fmaf(b.w,w0[192+j+2], m2))));
            m3 = fmaf(b.x,w0[j+3], fmaf(b.y,w0[64+j+3], fmaf(b.z,w0[128+j+3], fmaf(b.w,w0[192+j+3], m3))));
            m[j+0]=m0; m[j+1]=m1; m[j+2]=m2; m[j+3]=m3;
        }
    }
    vn2out = vn2;
}

// tanh(mx_norm/x_norm * artanh(x_norm)) * mx / mx_norm, then proj — in place.
__device__ __attribute__((always_inline)) inline void mob_scale_proj(
        float (&m)[64], float vn2) {
    float mn2 = 0.f;
    #pragma unroll
    for (int j = 0; j < 64; ++j) mn2 = fmaf(m[j], m[j], mn2);
    float xnorm = fmaxf(sqrtf(vn2), MINNORM_C);
    float mnorm = fmaxf(sqrtf(mn2), MINNORM_C);
    float z = fminf(xnorm, 1.0f - 1e-7f);                   // artanh clip
    float art = 0.5f * logf((1.0f + z) / (1.0f - z));
    float t = tanhf(mnorm / xnorm * art);
    float scale = (mn2 == 0.f) ? 0.f : (t / mnorm);         // zero_mx branch
    #pragma unroll
    for (int j = 0; j < 64; ++j) m[j] *= scale;
    float rn2 = 0.f;
    #pragma unroll
    for (int j = 0; j < 64; ++j) rn2 = fmaf(m[j], m[j], rn2);
    float rnorm = fmaxf(sqrtf(rn2), MINNORM_C);
    float f = (rnorm > MAXNORM_C) ? (MAXNORM_C / rnorm) : 1.0f;   // proj
    #pragma unroll
    for (int j = 0; j < 64; ++j) m[j] *= f;
}

// mobius_add with hyp_bias (in LDS) + proj factor; m updated in place,
// returns final proj scale f (applied at write time).
__device__ __attribute__((always_inline)) inline float bias_addf(
        float (&m)[64], const float* hbv) {
    float x2 = 0.f, xy = 0.f;
    #pragma unroll
    for (int j = 0; j < 64; ++j) {
        float h = hbv[j];
        x2 = fmaf(m[j], m[j], x2);
        xy = fmaf(m[j], h, xy);
    }
    float y2 = hbv[64];
    float A = 1.f + 2.f * xy + y2;
    float Bc = 1.f - x2;
    float den = 1.f + 2.f * xy + x2 * y2;
    float dinv = 1.f / fmaxf(den, MINNORM_C);
    float rn2 = 0.f;
    #pragma unroll
    for (int j = 0; j < 64; ++j) {
        float r = (A * m[j] + Bc * hbv[j]) * dinv;
        m[j] = r;
        rn2 = fmaf(r, r, rn2);
    }
    float rnorm = fmaxf(sqrtf(rn2), MINNORM_C);
    return (rnorm > MAXNORM_C) ? (MAXNORM_C / rnorm) : 1.0f;
}

// ---------- finalize: intra-wave hybrid pipes, UNFUSED phases ----------
// LDS stages the EVEN k-chunks of both matrices (2 x 8 KB); odd chunks
// stream via s_load inside mm1_hyb. Phases unfused (one 64-float acc live
// at a time -- in-thread fusion spills, refuted R3/R8): phase A -> store
// resA to out; phase B -> reload resA (same thread, L2-hot) + add.
__global__ __launch_bounds__(256, 2) void finalize_kernel(
    const float* __restrict__ x,
    const float* __restrict__ wt,    // 4 transposed 64x64 matrices
    const float* __restrict__ hb,    // 2 x 65
    float* __restrict__ out) {
    __shared__ float4 wlds[1024];               // [0..511]=A even chunks, [512..1023]=B
    __shared__ __align__(16) float hbs[68];
    int tid = threadIdx.x;
    int half = blockIdx.x & 1;

    const float4* wsrc4 = (const float4*)(wt + half * 8192);
    #pragma unroll
    for (int t = 0; t < 4; ++t) {
        int i = t * 256 + tid;                  // 0..1023
        int mtx = i >> 9;
        int rem = i & 511;
        int c = rem >> 6;
        int i4 = rem & 63;
        wlds[i] = wsrc4[mtx * 1024 + c * 128 + i4];
    }
    if (tid < 65) hbs[tid] = hb[half * 65 + tid];
    __syncthreads();

    int node = (blockIdx.x >> 1) * 256 + tid;
    bool valid = node < NN;
    int nc = valid ? node : NN - 1;
    float* op = out + (size_t)nc * 128 + half * 64;
    const float* wsA = wt + half * 8192;
    const float* wsB = wsA + 4096;

    // ---- phase A: proj(mobius_matvec(W, agg)) -> store resA to out
    {
        float m[64]; float vn2;
        mm1_hyb(op, wlds, wsA, m, vn2);
        mob_scale_proj(m, vn2);
        if (valid) {
            #pragma unroll
            for (int k0 = 0; k0 < 64; k0 += 4)
                *(float4*)(op + k0) = make_float4(m[k0], m[k0+1], m[k0+2], m[k0+3]);
        }
    }

    // ---- phase B: proj(mobius_add(proj(mobius_matvec(W_cc, x)), bias))
    {
        float m[64]; float vn2;
        mm1_hyb(x + (size_t)nc * 64, wlds + 512, wsB, m, vn2);
        mob_scale_proj(m, vn2);
        float f = bias_addf(m, hbs);
        if (valid) {
            #pragma unroll
            for (int k0 = 0; k0 < 64; k0 += 4) {
                float4 a = *(const float4*)(op + k0);   // resA, own write, L2-hot
                a.x += m[k0 + 0] * f;
                a.y += m[k0 + 1] * f;
                a.z += m[k0 + 2] * f;
                a.w += m[k0 + 3] * f;
                *(float4*)(op + k0) = a;
            }
        }
    }
}

extern "C" void kernel_launch(void* const* d_in, const int* in_sizes, int n_in,
                              void* d_out, int out_size, void* d_ws, size_t ws_size,
                              hipStream_t stream) {
    const float* x   = (const float*)d_in[0];
    const float* Wp  = (const float*)d_in[1];
    const float* Wpc = (const float*)d_in[2];
    const float* bp  = (const float*)d_in[3];
    const float* Wn  = (const float*)d_in[4];
    const float* Wnc = (const float*)d_in[5];
    const float* bn  = (const float*)d_in[6];
    const int* pei = (const int*)d_in[7];
    const int* nei = (const int*)d_in[8];
    float* out = (float*)d_out;

    int E1 = in_sizes[7] / 2;
    int E2 = in_sizes[8] / 2;
    int tot = E1 + E2;

    // ws layout (4-byte units):
    //   gcnt[NB2] | goffs[NB2] | gcursor[NB2] | pad | ndeg[2NN] | noffs[2NN]
    //   | hb[192] | wt[16384] | packed[tot] | esrc[tot]
    int*   gcnt    = (int*)d_ws;
    int*   goffs   = gcnt + NB2;
    int*   gcursor = goffs + NB2;
    int*   ndeg    = gcursor + NB2 + 2;          // align
    int*   noffs   = ndeg + 2 * NN;
    float* hbp     = (float*)(noffs + 2 * NN);
    float* wt      = hbp + 192;
    int*   packed  = (int*)(wt + 16384);
    int*   esrc    = packed + tot;

    hipMemsetAsync(gcnt, 0, NB2 * sizeof(int), stream);

    prep_transpose<<<64, 256, 0, stream>>>(Wp, Wpc, Wn, Wnc, wt);
    prep_bias<<<1, 64, 0, stream>>>(bp, bn, hbp);

    int nblk = (tot + 8191) / 8192;    // 391
    bucket_count<<<nblk, 256, 0, stream>>>(pei, E1, nei, E2, gcnt);
    bucket_scan<<<1, 256, 0, stream>>>(gcnt, goffs, gcursor);
    bucket_scatter<<<nblk, 256, 0, stream>>>(pei, E1, nei, E2, gcursor, packed);
    node_sort<<<NB2, 256, 0, stream>>>(goffs, gcnt, packed, esrc, ndeg, noffs);

    gather_kernel<<<(2 * NN * 64 + 255) / 256, 256, 0, stream>>>(noffs, ndeg, esrc, x, out);

    int fblocks = 2 * ((NN + 255) / 256);        // 782
    finalize_kernel<<<fblocks, 256, 0, stream>>>(x, wt, hbp, out);
}